// Round 2
// baseline (136.453 us; speedup 1.0000x reference)
//
#include <hip/hip_runtime.h>
#include <math.h>

#define VOCAB 50257
#define EMB   128
#define CTX   200
#define SLABS 4
#define ROWS_PER_SLAB (CTX / SLABS)          // 50
#define NT ((VOCAB + 15) / 16)               // 3142 row-tiles of 16
#define K3_BLOCKS 1571                       // NT/2: 2 tiles per block
#define HCHUNKS 32                           // k_hidden grid.x

// ---------------- K1: spart[slab][v] = sum of 50 rows of X ------------------
// grid (197, SLABS), block 256. Plain stores, no atomics.
// 10 independent accumulators: 788 blocks x 256 thr x 10 x 4B = 8.1 MB
// outstanding -> saturates HBM (need ~5.7 MB = 6.3 TB/s x ~900 ns).
__global__ void k_colsum(const float* __restrict__ X, float* __restrict__ spart) {
    int v = blockIdx.x * 256 + threadIdx.x;
    if (v >= VOCAB) return;
    const float* p = X + (size_t)(blockIdx.y * ROWS_PER_SLAB) * VOCAB + v;
    float a0 = 0.f, a1 = 0.f, a2 = 0.f, a3 = 0.f, a4 = 0.f;
    float a5 = 0.f, a6 = 0.f, a7 = 0.f, a8 = 0.f, a9 = 0.f;
#pragma unroll
    for (int i = 0; i < ROWS_PER_SLAB / 10; ++i) {   // 5 iters x 10 rows
        a0 += p[0 * (size_t)VOCAB];
        a1 += p[1 * (size_t)VOCAB];
        a2 += p[2 * (size_t)VOCAB];
        a3 += p[3 * (size_t)VOCAB];
        a4 += p[4 * (size_t)VOCAB];
        a5 += p[5 * (size_t)VOCAB];
        a6 += p[6 * (size_t)VOCAB];
        a7 += p[7 * (size_t)VOCAB];
        a8 += p[8 * (size_t)VOCAB];
        a9 += p[9 * (size_t)VOCAB];
        p += 10 * (size_t)VOCAB;
    }
    spart[(size_t)blockIdx.y * VOCAB + v] =
        (((a0 + a1) + (a2 + a3)) + ((a4 + a5) + (a6 + a7))) + (a8 + a9);
}

// ---------------- K2: hpart[chunk][e] = partial of sum_v s[v]*Wq[e,v] -------
// grid (HCHUNKS, 128), block 256. Plain store per block — no atomics, no memset.
// Already ~21 MB outstanding -> HBM-saturated; unchanged.
__global__ void k_hidden(const float* __restrict__ Wq, const float* __restrict__ spart,
                         float* __restrict__ hpart) {
    int e = blockIdx.y;
    const float* row = Wq + (size_t)e * VOCAB;
    float acc = 0.f;
    int stride = gridDim.x * blockDim.x;            // 8192
    for (int v = blockIdx.x * blockDim.x + threadIdx.x; v < VOCAB; v += stride) {
        float sv = spart[v] + spart[VOCAB + v] + spart[2 * VOCAB + v] + spart[3 * VOCAB + v];
        acc += sv * row[v];
    }
    for (int off = 32; off > 0; off >>= 1) acc += __shfl_down(acc, off, 64);
    __shared__ float wsum[4];
    int lane = threadIdx.x & 63, wid = threadIdx.x >> 6;
    if (lane == 0) wsum[wid] = acc;
    __syncthreads();
    if (threadIdx.x == 0)
        hpart[blockIdx.x * EMB + e] = (wsum[0] + wsum[1]) + (wsum[2] + wsum[3]);
}

// ---------------- K3: logits + per-block exp partial (no atomics) -----------
// grid K3_BLOCKS, block 256. h built per-block from the 32 hpart chunks (L2).
// 16 lanes per row v, two float4 loads per lane (512 B contiguous per row).
// 1571 blocks x 2 tiles: 12.9 MB outstanding, 24.5 waves/CU TLP.
__global__ void k_logits(const float* __restrict__ Ww, const float* __restrict__ bw,
                         const float* __restrict__ hpart, const float* __restrict__ bq,
                         const int* __restrict__ lenp,
                         float* __restrict__ logits, float* __restrict__ partials) {
    __shared__ float h[EMB];
    __shared__ float wsum[4];
    if (threadIdx.x < EMB) {
        float len = (float)lenp[0];
        float hr = 0.f;
#pragma unroll
        for (int c = 0; c < HCHUNKS; ++c) hr += hpart[c * EMB + threadIdx.x];
        h[threadIdx.x] = (hr + (float)CTX * bq[threadIdx.x]) / len;
    }
    __syncthreads();

    int group = threadIdx.x >> 4;                   // 0..15: row within tile
    int c     = threadIdx.x & 15;                   // lane within row
    float eacc = 0.f;

    for (int tile = blockIdx.x; tile < NT; tile += gridDim.x) {
        int v = tile * 16 + group;
        float acc = 0.f;
        if (v < VOCAB) {
            const float4* row = (const float4*)(Ww + (size_t)v * EMB);
            float4 w0 = row[c * 2];
            float4 w1 = row[c * 2 + 1];
            const float* hp = h + c * 8;
            acc = w0.x * hp[0] + w0.y * hp[1] + w0.z * hp[2] + w0.w * hp[3]
                + w1.x * hp[4] + w1.y * hp[5] + w1.z * hp[6] + w1.w * hp[7];
        }
        acc += __shfl_xor(acc, 1, 64);
        acc += __shfl_xor(acc, 2, 64);
        acc += __shfl_xor(acc, 4, 64);
        acc += __shfl_xor(acc, 8, 64);
        if (v < VOCAB && c == 0) {
            float lg = acc + bw[v];
            logits[v] = lg;
            eacc += expf(lg);
        }
    }

    for (int off = 32; off > 0; off >>= 1) eacc += __shfl_down(eacc, off, 64);
    int lane = threadIdx.x & 63, wid = threadIdx.x >> 6;
    if (lane == 0) wsum[wid] = eacc;
    __syncthreads();
    if (threadIdx.x == 0)
        partials[blockIdx.x] = (wsum[0] + wsum[1]) + (wsum[2] + wsum[3]);
}

// ---------------- K4: out[v] = logits[v] - log(sum partials) ----------------
// Each block redundantly reduces the 1571 partials (6 KB, L2-hot) — folds the
// reduce into the finalize pass, saving a dispatch.
__global__ void k_finalize(const float* __restrict__ logits,
                           const float* __restrict__ partials,
                           float* __restrict__ out) {
    __shared__ float wsum[4];
    __shared__ float lz;
    float acc = 0.f;
    for (int i = threadIdx.x; i < K3_BLOCKS; i += 256) acc += partials[i];
    for (int off = 32; off > 0; off >>= 1) acc += __shfl_down(acc, off, 64);
    int lane = threadIdx.x & 63, wid = threadIdx.x >> 6;
    if (lane == 0) wsum[wid] = acc;
    __syncthreads();
    if (threadIdx.x == 0)
        lz = logf((wsum[0] + wsum[1]) + (wsum[2] + wsum[3]));
    __syncthreads();
    int v = blockIdx.x * 256 + threadIdx.x;
    if (v < VOCAB) out[v] = logits[v] - lz;
}

extern "C" void kernel_launch(void* const* d_in, const int* in_sizes, int n_in,
                              void* d_out, int out_size, void* d_ws, size_t ws_size,
                              hipStream_t stream) {
    const float* X    = (const float*)d_in[0];   // [CTX, VOCAB]
    const int*   lenp = (const int*)d_in[1];     // scalar 200
    const float* Wq   = (const float*)d_in[2];   // [EMB, VOCAB]
    const float* bq   = (const float*)d_in[3];   // [EMB]
    const float* Ww   = (const float*)d_in[4];   // [VOCAB, EMB]
    const float* bw   = (const float*)d_in[5];   // [VOCAB]
    float* out = (float*)d_out;                  // [VOCAB]

    // Workspace layout (floats) — all plain stores, nothing needs zeroing:
    //   [0, 4096)                    hpart [32][128]
    //   [4096, 4096+1571)            partials (< 8192)
    //   [8192, 8192+4*V)             spart (4 slabs)
    //   logits aliases spart slab 0 — safe: k_hidden (last reader of spart)
    //   completes before k_logits (writer of logits) in stream order.
    float* ws       = (float*)d_ws;
    float* hpart    = ws;
    float* partials = ws + 4096;
    float* spart    = ws + 8192;
    float* logits   = spart;

    dim3 g1((VOCAB + 255) / 256, SLABS);
    k_colsum<<<g1, 256, 0, stream>>>(X, spart);

    dim3 g2(HCHUNKS, EMB);
    k_hidden<<<g2, 256, 0, stream>>>(Wq, spart, hpart);

    k_logits<<<K3_BLOCKS, 256, 0, stream>>>(Ww, bw, hpart, bq, lenp, logits, partials);

    k_finalize<<<(VOCAB + 255) / 256, 256, 0, stream>>>(logits, partials, out);
}